// Round 6
// baseline (274.945 us; speedup 1.0000x reference)
//
#include <hip/hip_runtime.h>
#include <math.h>

#define KTOP 20
#define R_MAX 2048
#define SPLIT 8

typedef float f4v __attribute__((ext_vector_type(4)));

// ---------------------------------------------------------------------------
// Kernel 1: sims_only — pure READ stream. grid = B*SPLIT x 256 thr.
// No LDS tile, no out stores. Each wave covers 64 rows; per iteration the
// wave's 4 groups of 16 lanes load 4 consecutive rows (1KB coalesced x4
// independent loads), reduce with the round-1-verified 16-lane butterfly.
// ~40 VGPR, launch_bounds(256,8) -> 100% occupancy; latency hidden by TLP.
// ---------------------------------------------------------------------------
__global__ __launch_bounds__(256, 8) void sims_only(
    const float* __restrict__ x,
    const int* __restrict__ qrels,
    float* __restrict__ sims,
    float* __restrict__ dns,
    int R)
{
    __shared__ float s_q[64];
    const int idx = blockIdx.x;
    const int b = idx >> 3;            // idx / SPLIT
    const int s = idx & (SPLIT - 1);
    const int t = threadIdx.x;
    const int qr = qrels[b];
    const long xbase = (long)b * R * 64;
    const long sbase = (long)b * R;

    // normalized query row (wave 0)
    if (t < 64) {
        float v = x[xbase + (long)qr * 64 + t];
        float ss = v * v;
#pragma unroll
        for (int m = 1; m < 64; m <<= 1) ss += __shfl_xor(ss, m, 64);
        s_q[t] = v / fmaxf(sqrtf(ss), 1e-12f);
    }
    __syncthreads();

    const int l16 = t & 15;
    const int gw  = (t >> 4) & 3;      // group within wave (4 rows / load)
    const int w   = t >> 6;            // wave id (4 waves)
    const float4 q4 = *(const float4*)(s_q + l16 * 4);

    const int row0 = s * (R / SPLIT) + w * 64;   // this wave's 64 rows

    // 4 iterations x 16 rows (4 independent 1KB wave-loads in flight)
#pragma unroll
    for (int it = 0; it < 4; ++it) {
        const int rbase = row0 + it * 16;
        float4 v[4];
#pragma unroll
        for (int j = 0; j < 4; ++j)
            v[j] = *(const float4*)(x + xbase + (long)(rbase + 4 * j + gw) * 64 + l16 * 4);
        float dot[4], ssv[4];
#pragma unroll
        for (int j = 0; j < 4; ++j) {
            dot[j] = v[j].x * q4.x + v[j].y * q4.y + v[j].z * q4.z + v[j].w * q4.w;
            ssv[j] = v[j].x * v[j].x + v[j].y * v[j].y + v[j].z * v[j].z + v[j].w * v[j].w;
        }
        // 8 interleaved butterfly chains (round-1-verified reduce order)
#pragma unroll
        for (int m = 1; m < 16; m <<= 1) {
#pragma unroll
            for (int j = 0; j < 4; ++j) {
                dot[j] += __shfl_xor(dot[j], m, 64);
                ssv[j] += __shfl_xor(ssv[j], m, 64);
            }
        }
        if (l16 == 0) {
#pragma unroll
            for (int j = 0; j < 4; ++j) {
                const int row = rbase + 4 * j + gw;
                float dn = fmaxf(sqrtf(ssv[j]), 1e-12f);
                sims[sbase + row] = (row == qr) ? -1.0f : dot[j] / dn;
                dns[sbase + row] = dn;
            }
        }
    }
}

// ---------------------------------------------------------------------------
// Kernel 2: copy_out — pure COPY x -> out (m13-structure clone).
// grid-stride, 4 independent dwordx4 loads per batch, NT stores,
// no LDS, ~24 VGPR, 100% occupancy. Runs after sims_only -> x is L3-warm.
// ---------------------------------------------------------------------------
__global__ __launch_bounds__(256, 8) void copy_out(
    const f4v* __restrict__ src,
    f4v* __restrict__ dst,
    long n4, long stride)
{
    long i = (long)blockIdx.x * 256 + threadIdx.x;
    for (; i + 3 * stride < n4; i += 4 * stride) {
        f4v a = src[i];
        f4v b = src[i + stride];
        f4v c = src[i + 2 * stride];
        f4v d = src[i + 3 * stride];
        __builtin_nontemporal_store(a, &dst[i]);
        __builtin_nontemporal_store(b, &dst[i + stride]);
        __builtin_nontemporal_store(c, &dst[i + 2 * stride]);
        __builtin_nontemporal_store(d, &dst[i + 3 * stride]);
    }
    for (; i < n4; i += stride)
        __builtin_nontemporal_store(src[i], &dst[i]);
}

// ---------------------------------------------------------------------------
// Kernel 3: selection + weighting + mixed-row write. grid = B x 256 threads.
// Verified logic (fp order identical to the round-1 passing kernel).
// ---------------------------------------------------------------------------
__global__ __launch_bounds__(256) void select_mix(
    const float* __restrict__ x,
    const int* __restrict__ qrels,
    const float* __restrict__ thr_raw,
    const float* __restrict__ str_raw,
    const float* __restrict__ wscale_p,
    const float* __restrict__ temp_p,
    const float* __restrict__ sims,
    const float* __restrict__ dns,
    float* __restrict__ out,
    int R)
{
    __shared__ float s_sims[R_MAX];
    __shared__ int   s_cand[R_MAX];
    __shared__ int   s_ncand;
    __shared__ float s_topv[KTOP];
    __shared__ int   s_topi[KTOP];
    __shared__ float s_dnsel[KTOP];
    __shared__ float s_adj[KTOP];
    __shared__ float s_strength;

    const int b = blockIdx.x;
    const int t = threadIdx.x;
    const int qr = qrels[b];
    const float threshold = 1.0f / (1.0f + expf(-thr_raw[0]));
    const long sbase = (long)b * R;
    const long xbase = (long)b * R * 64;

    if (t == 0) s_ncand = 0;
    __syncthreads();

    for (int i = t; i < R; i += 256) {
        float sv = sims[sbase + i];
        s_sims[i] = sv;
        if (sv > threshold) {
            int p = atomicAdd(&s_ncand, 1);
            s_cand[p] = i;
        }
    }
    __syncthreads();

    const int ncand = s_ncand;
    const int ksel = ncand < KTOP ? ncand : KTOP;

    if (t < 64) {
        float myv = 0.0f; int myi = 0;
        if (ncand > KTOP) {
            float lv[32]; int li[32];
#pragma unroll
            for (int j = 0; j < 32; ++j) {
                int i = t + 64 * j;
                if (i < ncand) { li[j] = s_cand[i]; lv[j] = s_sims[li[j]]; }
                else           { li[j] = 0x7fffffff; lv[j] = -INFINITY; }
            }
            for (int k = 0; k < KTOP; ++k) {
                float bv = -INFINITY; int bi = 0x7fffffff;
#pragma unroll
                for (int j = 0; j < 32; ++j)
                    if (lv[j] > bv || (lv[j] == bv && li[j] < bi)) { bv = lv[j]; bi = li[j]; }
#pragma unroll
                for (int m = 1; m < 64; m <<= 1) {
                    float v2 = __shfl_xor(bv, m, 64);
                    int   i2 = __shfl_xor(bi, m, 64);
                    if (v2 > bv || (v2 == bv && i2 < bi)) { bv = v2; bi = i2; }
                }
#pragma unroll
                for (int j = 0; j < 32; ++j) if (li[j] == bi) lv[j] = -INFINITY;
                if (t == k) { myv = bv; myi = bi; }
            }
        } else if (t < ksel) {
            myi = s_cand[t];
            myv = s_sims[myi];
        }
        if (t < ksel) {
            s_topv[t] = myv;
            s_topi[t] = myi;
            s_dnsel[t] = dns[sbase + myi];
        }
    }
    __syncthreads();

    if (t == 0) {
        float strength = (1.0f / (1.0f + expf(-str_raw[0]))) * 0.2f;
        float temp = fminf(fmaxf(temp_p[0], 0.1f), 10.0f);
        float wsc  = wscale_p[0];
        if (ksel > 0) {
            float m = -INFINITY;
            for (int k = 0; k < ksel; ++k) m = fmaxf(m, s_topv[k] / temp);
            float w[KTOP]; float wsum = 0.0f;
            for (int k = 0; k < ksel; ++k) { w[k] = expf(s_topv[k] / temp - m); wsum += w[k]; }
            float adj[KTOP]; float asum = 0.0f;
            for (int k = 0; k < ksel; ++k) {
                float tv = s_topv[k];
                float sw = 1.0f / (1.0f + expf(-(tv - threshold) * 10.0f));
                float a  = (w[k] / wsum) * sw * (1.0f + wsc * tv);
                adj[k] = a; asum += a;
            }
            for (int k = 0; k < ksel; ++k)
                s_adj[k] = (adj[k] / (asum + 1e-8f)) / s_dnsel[k];
        }
        s_strength = strength;
    }
    __syncthreads();

    if (t < 64 && ksel > 0) {
        const long qb = xbase + (long)qr * 64 + t;
        float qo = x[qb];
        float acc = 0.0f;
        for (int k = 0; k < ksel; ++k)
            acc += s_adj[k] * x[xbase + (long)s_topi[k] * 64 + t];
        float st = s_strength;
        out[qb] = (1.0f - st) * qo + st * acc;
    }
}

// ---------------------------------------------------------------------------
// Fallback: original verified fused kernel (odd shapes / no workspace).
// ---------------------------------------------------------------------------
__global__ __launch_bounds__(1024) void fused_enhancer(
    const float* __restrict__ x,
    const int* __restrict__ qrels,
    const float* __restrict__ thr_raw,
    const float* __restrict__ str_raw,
    const float* __restrict__ wscale_p,
    const float* __restrict__ temp_p,
    float* __restrict__ out, int R)
{
    __shared__ float s_q[64];
    __shared__ float s_sims[R_MAX];
    __shared__ float s_dn[R_MAX];
    __shared__ int   s_cand[R_MAX];
    __shared__ int   s_ncand;
    __shared__ float s_topv[KTOP];
    __shared__ int   s_topi[KTOP];
    __shared__ float s_adj[KTOP];
    __shared__ float s_strength;

    const int b = blockIdx.x;
    const int t = threadIdx.x;
    const int qr = qrels[b];
    const float threshold = 1.0f / (1.0f + expf(-thr_raw[0]));

    if (t == 0) s_ncand = 0;

    if (t < 64) {
        float v = x[((long)b * R + qr) * 64 + t];
        float ss = v * v;
#pragma unroll
        for (int m = 1; m < 64; m <<= 1) ss += __shfl_xor(ss, m, 64);
        s_q[t] = v / fmaxf(sqrtf(ss), 1e-12f);
    }
    __syncthreads();

    const int grp = t >> 4, l16 = t & 15;
    const float4 q4 = *(const float4*)(s_q + l16 * 4);
    const long xbase = (long)b * R * 64;
    for (int row = grp; row < R; row += 64) {
        long base = xbase + (long)row * 64 + l16 * 4;
        const float4 v = *(const float4*)(x + base);
        *(float4*)(out + base) = v;
        float dot = v.x * q4.x + v.y * q4.y + v.z * q4.z + v.w * q4.w;
        float ss  = v.x * v.x + v.y * v.y + v.z * v.z + v.w * v.w;
#pragma unroll
        for (int m = 1; m < 16; m <<= 1) {
            dot += __shfl_xor(dot, m, 64);
            ss  += __shfl_xor(ss,  m, 64);
        }
        if (l16 == 0) {
            float dn  = fmaxf(sqrtf(ss), 1e-12f);
            float sim = (row == qr) ? -1.0f : dot / dn;
            s_sims[row] = sim;
            s_dn[row]   = dn;
            if (sim > threshold) {
                int p = atomicAdd(&s_ncand, 1);
                s_cand[p] = row;
            }
        }
    }
    __syncthreads();

    const int ncand = s_ncand;
    const int ksel = ncand < KTOP ? ncand : KTOP;

    if (t < 64) {
        if (ncand > KTOP) {
            float lv[32]; int li[32];
#pragma unroll
            for (int j = 0; j < 32; ++j) {
                int i = t + 64 * j;
                if (i < ncand) { li[j] = s_cand[i]; lv[j] = s_sims[li[j]]; }
                else           { li[j] = 0x7fffffff; lv[j] = -INFINITY; }
            }
            for (int k = 0; k < KTOP; ++k) {
                float bv = -INFINITY; int bi = 0x7fffffff;
#pragma unroll
                for (int j = 0; j < 32; ++j) {
                    if (lv[j] > bv || (lv[j] == bv && li[j] < bi)) { bv = lv[j]; bi = li[j]; }
                }
#pragma unroll
                for (int m = 1; m < 64; m <<= 1) {
                    float v2 = __shfl_xor(bv, m, 64);
                    int   i2 = __shfl_xor(bi, m, 64);
                    if (v2 > bv || (v2 == bv && i2 < bi)) { bv = v2; bi = i2; }
                }
#pragma unroll
                for (int j = 0; j < 32; ++j) if (li[j] == bi) lv[j] = -INFINITY;
                if (t == 0) { s_topv[k] = bv; s_topi[k] = bi; }
            }
        } else if (t == 0) {
            for (int k = 0; k < ksel; ++k) {
                int idx = s_cand[k];
                s_topi[k] = idx;
                s_topv[k] = s_sims[idx];
            }
        }
    }

    if (t == 0) {
        float strength = (1.0f / (1.0f + expf(-str_raw[0]))) * 0.2f;
        float temp = fminf(fmaxf(temp_p[0], 0.1f), 10.0f);
        float wsc  = wscale_p[0];
        if (ksel > 0) {
            float m = -INFINITY;
            for (int k = 0; k < ksel; ++k) m = fmaxf(m, s_topv[k] / temp);
            float w[KTOP]; float wsum = 0.0f;
            for (int k = 0; k < ksel; ++k) { w[k] = expf(s_topv[k] / temp - m); wsum += w[k]; }
            float adj[KTOP]; float asum = 0.0f;
            for (int k = 0; k < ksel; ++k) {
                float tv = s_topv[k];
                float sw = 1.0f / (1.0f + expf(-(tv - threshold) * 10.0f));
                float a  = (w[k] / wsum) * sw * (1.0f + wsc * tv);
                adj[k] = a; asum += a;
            }
            for (int k = 0; k < ksel; ++k)
                s_adj[k] = (adj[k] / (asum + 1e-8f)) / s_dn[s_topi[k]];
        }
        s_strength = strength;
    }
    __syncthreads();

    if (t < 64 && ksel > 0) {
        long qb = ((long)b * R + qr) * 64 + t;
        float qo = x[qb];
        float acc = 0.0f;
        for (int k = 0; k < ksel; ++k)
            acc += s_adj[k] * x[((long)b * R + s_topi[k]) * 64 + t];
        float st = s_strength;
        out[qb] = (1.0f - st) * qo + st * acc;
    }
}

extern "C" void kernel_launch(void* const* d_in, const int* in_sizes, int n_in,
                              void* d_out, int out_size, void* d_ws, size_t ws_size,
                              hipStream_t stream) {
    const float* x      = (const float*)d_in[0];
    const int*   qrels  = (const int*)d_in[1];
    const float* thr    = (const float*)d_in[2];
    const float* str    = (const float*)d_in[3];
    const float* wscale = (const float*)d_in[4];
    const float* temp   = (const float*)d_in[5];
    float* out = (float*)d_out;

    const int B = in_sizes[1];
    const int D = 64;
    const int R = in_sizes[0] / (B * D);
    (void)D;

    const size_t need = (size_t)B * R * 2 * sizeof(float);
    if (d_ws != nullptr && ws_size >= need && (R % (SPLIT * 256)) == 0 && R <= R_MAX) {
        float* sims = (float*)d_ws;
        float* dns  = sims + (size_t)B * R;
        const long n4 = (long)B * R * 16;            // total float4 count
        const int  cgrid = 2048;
        const long cstride = (long)cgrid * 256;
        sims_only<<<B * SPLIT, 256, 0, stream>>>(x, qrels, sims, dns, R);
        copy_out<<<cgrid, 256, 0, stream>>>((const f4v*)x, (f4v*)out, n4, cstride);
        select_mix<<<B, 256, 0, stream>>>(x, qrels, thr, str, wscale, temp,
                                          sims, dns, out, R);
    } else {
        fused_enhancer<<<B, 1024, 0, stream>>>(x, qrels, thr, str, wscale, temp, out, R);
    }
}

// Round 7
// 252.435 us; speedup vs baseline: 1.0892x; 1.0892x over previous
//
#include <hip/hip_runtime.h>
#include <math.h>

#define KTOP 20
#define R_MAX 2048
#define SPLIT 8
#define ST 66   // LDS row stride in floats: 64 data + 2 pad

typedef float f4v __attribute__((ext_vector_type(4)));

// ---------------------------------------------------------------------------
// Kernel A: streaming pass (round-4 structure, BEST measured: 81 us).
// grid = B*SPLIT blocks x 256 threads (4 waves). Each wave owns 64 rows as
// two 32-row half-tiles: burst-load 16x dwordx4, stage to LDS, per-lane dot
// (2 lanes/row, ONE shfl_xor(32)).
// SINGLE CHANGE vs round 4: out stores are NON-TEMPORAL. out is write-only
// and never re-read; plain stores write-allocate in L2/L3 and evict x
// (r4: FETCH=66MB = half of x re-fetched). NT keeps x L3-resident.
// ---------------------------------------------------------------------------
static_assert(sizeof(float) * (4 * 32 * ST + 64) < 36 * 1024, "LDS budget");

__global__ __launch_bounds__(256, 3) void stream_sims(
    const float* __restrict__ x,
    const int* __restrict__ qrels,
    float* __restrict__ out,
    float* __restrict__ sims,
    float* __restrict__ dns,
    int R)
{
    __shared__ float s_q[64];
    __shared__ float s_tile[4][32 * ST];   // ~33.8 KB

    const int blk = blockIdx.x;
    const int b = blk >> 3;            // blk / SPLIT
    const int s = blk & (SPLIT - 1);
    const int t = threadIdx.x;
    const int qr = qrels[b];
    const long xbase = (long)b * R * 64;
    const long sbase = (long)b * R;

    // normalized query row (wave 0)
    if (t < 64) {
        float v = x[xbase + (long)qr * 64 + t];
        float ss = v * v;
#pragma unroll
        for (int m = 1; m < 64; m <<= 1) ss += __shfl_xor(ss, m, 64);
        s_q[t] = v / fmaxf(sqrtf(ss), 1e-12f);
    }
    __syncthreads();

    const int wid = t >> 6, lane = t & 63;
    const int g4 = lane >> 4, l16 = lane & 15;   // load mapping: 4 rows x 16 lanes
    const int h = lane >> 5, l32 = lane & 31;    // dot mapping: 2 lanes per row

    float4 q[8];
#pragma unroll
    for (int k = 0; k < 8; ++k) q[k] = *(const float4*)(s_q + h * 32 + k * 4);

    const int row0 = s * (R / SPLIT) + wid * 64;   // this wave's 64 rows
    const int rA0 = row0, rB0 = row0 + 32;
    float* lds = &s_tile[wid][0];

    // ---- burst loads: 16 dwordx4 in flight per wave ----
    float4 vA[8], vB[8];
#pragma unroll
    for (int j = 0; j < 8; ++j)
        vA[j] = *(const float4*)(x + xbase + (long)(rA0 + g4 + 4 * j) * 64 + l16 * 4);
#pragma unroll
    for (int j = 0; j < 8; ++j)
        vB[j] = *(const float4*)(x + xbase + (long)(rB0 + g4 + 4 * j) * 64 + l16 * 4);

    // ---- half-tile A: NT-store out + stage LDS ----
#pragma unroll
    for (int j = 0; j < 8; ++j) {
        const int r = g4 + 4 * j;
        __builtin_nontemporal_store(*(const f4v*)&vA[j],
            (f4v*)(out + xbase + (long)(rA0 + r) * 64 + l16 * 4));
        float* p = lds + r * ST + l16 * 4;
        *(float2*)(p)     = make_float2(vA[j].x, vA[j].y);
        *(float2*)(p + 2) = make_float2(vA[j].z, vA[j].w);
    }
    // ---- dot A: lane owns half of row rA0+l32 ----
    {
        float dot = 0.0f, ssv = 0.0f;
        const float* rp = lds + l32 * ST + h * 32;
#pragma unroll
        for (int k = 0; k < 16; ++k) {
            float2 rv = *(const float2*)(rp + 2 * k);
            const float* qf = (const float*)&q[k >> 1];
            float qa = qf[(2 * k) & 3], qb = qf[(2 * k + 1) & 3];
            dot += rv.x * qa + rv.y * qb;
            ssv += rv.x * rv.x + rv.y * rv.y;
        }
        dot += __shfl_xor(dot, 32, 64);
        ssv += __shfl_xor(ssv, 32, 64);
        if (h == 0) {
            const int row = rA0 + l32;
            float dn = fmaxf(sqrtf(ssv), 1e-12f);
            sims[sbase + row] = (row == qr) ? -1.0f : dot / dn;
            dns[sbase + row] = dn;
        }
    }

    // ---- half-tile B: NT-store out + stage LDS (same tile; DS in-order) ----
#pragma unroll
    for (int j = 0; j < 8; ++j) {
        const int r = g4 + 4 * j;
        __builtin_nontemporal_store(*(const f4v*)&vB[j],
            (f4v*)(out + xbase + (long)(rB0 + r) * 64 + l16 * 4));
        float* p = lds + r * ST + l16 * 4;
        *(float2*)(p)     = make_float2(vB[j].x, vB[j].y);
        *(float2*)(p + 2) = make_float2(vB[j].z, vB[j].w);
    }
    // ---- dot B ----
    {
        float dot = 0.0f, ssv = 0.0f;
        const float* rp = lds + l32 * ST + h * 32;
#pragma unroll
        for (int k = 0; k < 16; ++k) {
            float2 rv = *(const float2*)(rp + 2 * k);
            const float* qf = (const float*)&q[k >> 1];
            float qa = qf[(2 * k) & 3], qb = qf[(2 * k + 1) & 3];
            dot += rv.x * qa + rv.y * qb;
            ssv += rv.x * rv.x + rv.y * rv.y;
        }
        dot += __shfl_xor(dot, 32, 64);
        ssv += __shfl_xor(ssv, 32, 64);
        if (h == 0) {
            const int row = rB0 + l32;
            float dn = fmaxf(sqrtf(ssv), 1e-12f);
            sims[sbase + row] = (row == qr) ? -1.0f : dot / dn;
            dns[sbase + row] = dn;
        }
    }
}

// ---------------------------------------------------------------------------
// Kernel B: selection + weighting + mixed-row write. grid = B x 256 threads.
// Verified logic (fp order identical to the round-1 passing kernel).
// ---------------------------------------------------------------------------
__global__ __launch_bounds__(256) void select_mix(
    const float* __restrict__ x,
    const int* __restrict__ qrels,
    const float* __restrict__ thr_raw,
    const float* __restrict__ str_raw,
    const float* __restrict__ wscale_p,
    const float* __restrict__ temp_p,
    const float* __restrict__ sims,
    const float* __restrict__ dns,
    float* __restrict__ out,
    int R)
{
    __shared__ float s_sims[R_MAX];
    __shared__ int   s_cand[R_MAX];
    __shared__ int   s_ncand;
    __shared__ float s_topv[KTOP];
    __shared__ int   s_topi[KTOP];
    __shared__ float s_dnsel[KTOP];
    __shared__ float s_adj[KTOP];
    __shared__ float s_strength;

    const int b = blockIdx.x;
    const int t = threadIdx.x;
    const int qr = qrels[b];
    const float threshold = 1.0f / (1.0f + expf(-thr_raw[0]));
    const long sbase = (long)b * R;
    const long xbase = (long)b * R * 64;

    if (t == 0) s_ncand = 0;
    __syncthreads();

    for (int i = t; i < R; i += 256) {
        float sv = sims[sbase + i];
        s_sims[i] = sv;
        if (sv > threshold) {
            int p = atomicAdd(&s_ncand, 1);
            s_cand[p] = i;
        }
    }
    __syncthreads();

    const int ncand = s_ncand;
    const int ksel = ncand < KTOP ? ncand : KTOP;

    if (t < 64) {
        float myv = 0.0f; int myi = 0;
        if (ncand > KTOP) {
            float lv[32]; int li[32];
#pragma unroll
            for (int j = 0; j < 32; ++j) {
                int i = t + 64 * j;
                if (i < ncand) { li[j] = s_cand[i]; lv[j] = s_sims[li[j]]; }
                else           { li[j] = 0x7fffffff; lv[j] = -INFINITY; }
            }
            for (int k = 0; k < KTOP; ++k) {
                float bv = -INFINITY; int bi = 0x7fffffff;
#pragma unroll
                for (int j = 0; j < 32; ++j)
                    if (lv[j] > bv || (lv[j] == bv && li[j] < bi)) { bv = lv[j]; bi = li[j]; }
#pragma unroll
                for (int m = 1; m < 64; m <<= 1) {
                    float v2 = __shfl_xor(bv, m, 64);
                    int   i2 = __shfl_xor(bi, m, 64);
                    if (v2 > bv || (v2 == bv && i2 < bi)) { bv = v2; bi = i2; }
                }
#pragma unroll
                for (int j = 0; j < 32; ++j) if (li[j] == bi) lv[j] = -INFINITY;
                if (t == k) { myv = bv; myi = bi; }
            }
        } else if (t < ksel) {
            myi = s_cand[t];
            myv = s_sims[myi];
        }
        if (t < ksel) {
            s_topv[t] = myv;
            s_topi[t] = myi;
            s_dnsel[t] = dns[sbase + myi];
        }
    }
    __syncthreads();

    if (t == 0) {
        float strength = (1.0f / (1.0f + expf(-str_raw[0]))) * 0.2f;
        float temp = fminf(fmaxf(temp_p[0], 0.1f), 10.0f);
        float wsc  = wscale_p[0];
        if (ksel > 0) {
            float m = -INFINITY;
            for (int k = 0; k < ksel; ++k) m = fmaxf(m, s_topv[k] / temp);
            float w[KTOP]; float wsum = 0.0f;
            for (int k = 0; k < ksel; ++k) { w[k] = expf(s_topv[k] / temp - m); wsum += w[k]; }
            float adj[KTOP]; float asum = 0.0f;
            for (int k = 0; k < ksel; ++k) {
                float tv = s_topv[k];
                float sw = 1.0f / (1.0f + expf(-(tv - threshold) * 10.0f));
                float a  = (w[k] / wsum) * sw * (1.0f + wsc * tv);
                adj[k] = a; asum += a;
            }
            for (int k = 0; k < ksel; ++k)
                s_adj[k] = (adj[k] / (asum + 1e-8f)) / s_dnsel[k];
        }
        s_strength = strength;
    }
    __syncthreads();

    if (t < 64 && ksel > 0) {
        const long qb = xbase + (long)qr * 64 + t;
        float qo = x[qb];
        float acc = 0.0f;
        for (int k = 0; k < ksel; ++k)
            acc += s_adj[k] * x[xbase + (long)s_topi[k] * 64 + t];
        float st = s_strength;
        out[qb] = (1.0f - st) * qo + st * acc;
    }
}

// ---------------------------------------------------------------------------
// Fallback: original verified fused kernel (odd shapes / no workspace).
// ---------------------------------------------------------------------------
__global__ __launch_bounds__(1024) void fused_enhancer(
    const float* __restrict__ x,
    const int* __restrict__ qrels,
    const float* __restrict__ thr_raw,
    const float* __restrict__ str_raw,
    const float* __restrict__ wscale_p,
    const float* __restrict__ temp_p,
    float* __restrict__ out, int R)
{
    __shared__ float s_q[64];
    __shared__ float s_sims[R_MAX];
    __shared__ float s_dn[R_MAX];
    __shared__ int   s_cand[R_MAX];
    __shared__ int   s_ncand;
    __shared__ float s_topv[KTOP];
    __shared__ int   s_topi[KTOP];
    __shared__ float s_adj[KTOP];
    __shared__ float s_strength;

    const int b = blockIdx.x;
    const int t = threadIdx.x;
    const int qr = qrels[b];
    const float threshold = 1.0f / (1.0f + expf(-thr_raw[0]));

    if (t == 0) s_ncand = 0;

    if (t < 64) {
        float v = x[((long)b * R + qr) * 64 + t];
        float ss = v * v;
#pragma unroll
        for (int m = 1; m < 64; m <<= 1) ss += __shfl_xor(ss, m, 64);
        s_q[t] = v / fmaxf(sqrtf(ss), 1e-12f);
    }
    __syncthreads();

    const int grp = t >> 4, l16 = t & 15;
    const float4 q4 = *(const float4*)(s_q + l16 * 4);
    const long xbase = (long)b * R * 64;
    for (int row = grp; row < R; row += 64) {
        long base = xbase + (long)row * 64 + l16 * 4;
        const float4 v = *(const float4*)(x + base);
        *(float4*)(out + base) = v;
        float dot = v.x * q4.x + v.y * q4.y + v.z * q4.z + v.w * q4.w;
        float ss  = v.x * v.x + v.y * v.y + v.z * v.z + v.w * v.w;
#pragma unroll
        for (int m = 1; m < 16; m <<= 1) {
            dot += __shfl_xor(dot, m, 64);
            ss  += __shfl_xor(ss,  m, 64);
        }
        if (l16 == 0) {
            float dn  = fmaxf(sqrtf(ss), 1e-12f);
            float sim = (row == qr) ? -1.0f : dot / dn;
            s_sims[row] = sim;
            s_dn[row]   = dn;
            if (sim > threshold) {
                int p = atomicAdd(&s_ncand, 1);
                s_cand[p] = row;
            }
        }
    }
    __syncthreads();

    const int ncand = s_ncand;
    const int ksel = ncand < KTOP ? ncand : KTOP;

    if (t < 64) {
        if (ncand > KTOP) {
            float lv[32]; int li[32];
#pragma unroll
            for (int j = 0; j < 32; ++j) {
                int i = t + 64 * j;
                if (i < ncand) { li[j] = s_cand[i]; lv[j] = s_sims[li[j]]; }
                else           { li[j] = 0x7fffffff; lv[j] = -INFINITY; }
            }
            for (int k = 0; k < KTOP; ++k) {
                float bv = -INFINITY; int bi = 0x7fffffff;
#pragma unroll
                for (int j = 0; j < 32; ++j) {
                    if (lv[j] > bv || (lv[j] == bv && li[j] < bi)) { bv = lv[j]; bi = li[j]; }
                }
#pragma unroll
                for (int m = 1; m < 64; m <<= 1) {
                    float v2 = __shfl_xor(bv, m, 64);
                    int   i2 = __shfl_xor(bi, m, 64);
                    if (v2 > bv || (v2 == bv && i2 < bi)) { bv = v2; bi = i2; }
                }
#pragma unroll
                for (int j = 0; j < 32; ++j) if (li[j] == bi) lv[j] = -INFINITY;
                if (t == 0) { s_topv[k] = bv; s_topi[k] = bi; }
            }
        } else if (t == 0) {
            for (int k = 0; k < ksel; ++k) {
                int idx = s_cand[k];
                s_topi[k] = idx;
                s_topv[k] = s_sims[idx];
            }
        }
    }

    if (t == 0) {
        float strength = (1.0f / (1.0f + expf(-str_raw[0]))) * 0.2f;
        float temp = fminf(fmaxf(temp_p[0], 0.1f), 10.0f);
        float wsc  = wscale_p[0];
        if (ksel > 0) {
            float m = -INFINITY;
            for (int k = 0; k < ksel; ++k) m = fmaxf(m, s_topv[k] / temp);
            float w[KTOP]; float wsum = 0.0f;
            for (int k = 0; k < ksel; ++k) { w[k] = expf(s_topv[k] / temp - m); wsum += w[k]; }
            float adj[KTOP]; float asum = 0.0f;
            for (int k = 0; k < ksel; ++k) {
                float tv = s_topv[k];
                float sw = 1.0f / (1.0f + expf(-(tv - threshold) * 10.0f));
                float a  = (w[k] / wsum) * sw * (1.0f + wsc * tv);
                adj[k] = a; asum += a;
            }
            for (int k = 0; k < ksel; ++k)
                s_adj[k] = (adj[k] / (asum + 1e-8f)) / s_dn[s_topi[k]];
        }
        s_strength = strength;
    }
    __syncthreads();

    if (t < 64 && ksel > 0) {
        long qb = ((long)b * R + qr) * 64 + t;
        float qo = x[qb];
        float acc = 0.0f;
        for (int k = 0; k < ksel; ++k)
            acc += s_adj[k] * x[((long)b * R + s_topi[k]) * 64 + t];
        float st = s_strength;
        out[qb] = (1.0f - st) * qo + st * acc;
    }
}

extern "C" void kernel_launch(void* const* d_in, const int* in_sizes, int n_in,
                              void* d_out, int out_size, void* d_ws, size_t ws_size,
                              hipStream_t stream) {
    const float* x      = (const float*)d_in[0];
    const int*   qrels  = (const int*)d_in[1];
    const float* thr    = (const float*)d_in[2];
    const float* str    = (const float*)d_in[3];
    const float* wscale = (const float*)d_in[4];
    const float* temp   = (const float*)d_in[5];
    float* out = (float*)d_out;

    const int B = in_sizes[1];
    const int D = 64;
    const int R = in_sizes[0] / (B * D);
    (void)D;

    const size_t need = (size_t)B * R * 2 * sizeof(float);
    if (d_ws != nullptr && ws_size >= need && (R % (SPLIT * 256)) == 0 && R <= R_MAX) {
        float* sims = (float*)d_ws;
        float* dns  = sims + (size_t)B * R;
        stream_sims<<<B * SPLIT, 256, 0, stream>>>(x, qrels, out, sims, dns, R);
        select_mix<<<B, 256, 0, stream>>>(x, qrels, thr, str, wscale, temp,
                                          sims, dns, out, R);
    } else {
        fused_enhancer<<<B, 1024, 0, stream>>>(x, qrels, thr, str, wscale, temp, out, R);
    }
}